// Round 2
// baseline (551.621 us; speedup 1.0000x reference)
//
#include <hip/hip_runtime.h>
#include <stdint.h>

// ---------------------------------------------------------------------------
// Fused 2-layer tanh RNN + FC head for MI355X (gfx950).  Round 2.
//
// B=512,T=1024,I=32,H1=128,H2=64,C=10.  32 blocks x 768 threads (12 waves),
// 16 batch rows per block; the whole serial T-loop lives in the block.
// Waves 0..7:  layer-1 tile w (16 ch) -- 5 MFMA/step, 4 tanh/lane.
// Waves 8..11: layer-2 tile w-8       -- 6 MFMA/step, 4 tanh/lane (lagged 1).
// All weights live in registers as fp16 MFMA A-fragments for the whole run.
// KEY FIX vs round 1: per-step barrier is `s_waitcnt lgkmcnt(0); s_barrier`
// (NOT __syncthreads, which drains vmcnt(0) and killed the x prefetch).
// x prefetch distance = 4 steps, compile-time register slot rotation.
// Input projection for step t+1 is computed during step t (off-chain).
// ---------------------------------------------------------------------------

typedef _Float16 f16x8 __attribute__((ext_vector_type(8)));
typedef float f32x4 __attribute__((ext_vector_type(4)));

#define MFMA_F16(A, B, C) __builtin_amdgcn_mfma_f32_16x16x32_f16((A), (B), (C), 0, 0, 0)

__device__ __forceinline__ float tanh_fast(float x) {
  // tanh(x) = 1 - 2/(1 + 2^(2x*log2e)); abs err ~1e-6.
  float t = __builtin_amdgcn_exp2f(x * 2.88539008177792681472f);
  return 1.0f - 2.0f * __builtin_amdgcn_rcpf(t + 1.0f);
}

__device__ __forceinline__ uint32_t pk16(float a, float b) {
  return __builtin_bit_cast(uint32_t, __builtin_amdgcn_cvt_pkrtz(a, b));
}

// LDS-only barrier: drain ds ops, rendezvous. Leaves global loads in flight.
__device__ __forceinline__ void sync_lds() {
  asm volatile("s_waitcnt lgkmcnt(0)\n\ts_barrier" ::: "memory");
}

__global__ __launch_bounds__(768) void rnn_fused(
    const float* __restrict__ x,
    const float* __restrict__ Wih1, const float* __restrict__ Whh1,
    const float* __restrict__ bih1, const float* __restrict__ bhh1,
    const float* __restrict__ Wih2, const float* __restrict__ Whh2,
    const float* __restrict__ bih2, const float* __restrict__ bhh2,
    const float* __restrict__ Wfc,  const float* __restrict__ bfc,
    float* __restrict__ out)
{
  constexpr int T = 1024, I = 32, H1 = 128, H2 = 64, BB = 16;

  // LDS map (bytes):
  //   H1[0] @ 0      (16 rows x 128 f16 = 4096B)  h1, double-buffered
  //   H1[1] @ 4096
  //   H2[0] @ 8192   (16 rows x  64 f16 = 2048B)  h2, double-buffered
  //   H2[1] @ 10240
  //   h2f   @ 12288  (16 rows x  64 f32 = 4096B)  final h2 for FC
  __shared__ __align__(16) unsigned char smem[16384];

  const int tid  = threadIdx.x;
  const int w    = tid >> 6;      // wave 0..11
  const int lane = tid & 63;
  const int g    = lane >> 4;     // k-group 0..3
  const int n    = lane & 15;     // batch col 0..15
  const int b0   = blockIdx.x * BB;

  // ---- zero h1(0), h2(0) ----
  {
    uint32_t* p = (uint32_t*)smem;
    for (int i = tid; i < 1024; i += 768) p[i] = 0u;   // H1[0]
    uint32_t* q = (uint32_t*)(smem + 8192);
    for (int i = tid; i < 512; i += 768) q[i] = 0u;    // H2[0]
  }

  auto cvt8 = [](const float* s) -> f16x8 {
    f16x8 r;
#pragma unroll
    for (int j = 0; j < 8; ++j) r[j] = (_Float16)s[j];
    return r;
  };

  // shared read offsets (B-frag reads), swizzled: slot ^= (n&7), 16B slots.
  int roff1[4];
#pragma unroll
  for (int k4 = 0; k4 < 4; ++k4)
    roff1[k4] = n * 256 + (((k4 * 4 + g) ^ (n & 7)) << 4);

  __syncthreads();  // zeroing visible to all (once; vmcnt drain OK here)

  if (w < 8) {
    // ================= layer-1 wave: channels 16w .. 16w+15 =================
    f16x8 aU[4], aI1;
#pragma unroll
    for (int k4 = 0; k4 < 4; ++k4)
      aU[k4] = cvt8(Whh1 + (16 * w + n) * H1 + k4 * 32 + g * 8);
    aI1 = cvt8(Wih1 + (16 * w + n) * I + g * 8);
    f32x4 bias1;
#pragma unroll
    for (int r = 0; r < 4; ++r) bias1[r] = bih1[16 * w + g * 4 + r] + bhh1[16 * w + g * 4 + r];

    const int woff = n * 256 + (((2 * w + (g >> 1)) ^ (n & 7)) << 4) + (g & 1) * 8;
    const float* xp = x + (size_t)(b0 + n) * T * I + g * 8;

    // x queue: 4 slots (prefetch distance 4), compile-time rotation.
    f32x4 q0a = *(const f32x4*)(xp + 0 * I), q0b = *(const f32x4*)(xp + 0 * I + 4);
    f32x4 q1a = *(const f32x4*)(xp + 1 * I), q1b = *(const f32x4*)(xp + 1 * I + 4);
    f32x4 q2a = *(const f32x4*)(xp + 2 * I), q2b = *(const f32x4*)(xp + 2 * I + 4);
    f32x4 q3a = *(const f32x4*)(xp + 3 * I), q3b = *(const f32x4*)(xp + 3 * I + 4);

    // input projection for step 0 (C-init of the recurrent chain)
    f32x4 accI;
    {
      union { uint32_t u[4]; f16x8 v; } tmp;
      tmp.u[0] = pk16(q0a[0], q0a[1]); tmp.u[1] = pk16(q0a[2], q0a[3]);
      tmp.u[2] = pk16(q0b[0], q0b[1]); tmp.u[3] = pk16(q0b[2], q0b[3]);
      accI = MFMA_F16(aI1, tmp.v, bias1);
    }

    auto stepL1 = [&](int t, int cur, f32x4& la, f32x4& lb,
                      const f32x4& pa, const f32x4& pb) {
      const char* H1c = (const char*)smem + cur * 4096;
      char*       H1n = (char*)smem + (cur ^ 1) * 4096;
      // read h1(t) fragments first
      f16x8 b1k0 = *(const f16x8*)(H1c + roff1[0]);
      f16x8 b1k1 = *(const f16x8*)(H1c + roff1[1]);
      f16x8 b1k2 = *(const f16x8*)(H1c + roff1[2]);
      f16x8 b1k3 = *(const f16x8*)(H1c + roff1[3]);
      // prefetch x(t+4) into the slot that held x(t) (already consumed)
      if (t + 4 < T) {
        la = *(const f32x4*)(xp + (t + 4) * I);
        lb = *(const f32x4*)(xp + (t + 4) * I + 4);
      }
      // recurrent chain, split into two 2-deep chains
      f32x4 zero = {0.f, 0.f, 0.f, 0.f};
      f32x4 aA = MFMA_F16(aU[0], b1k0, accI);
      f32x4 aB = MFMA_F16(aU[2], b1k2, zero);
      aA = MFMA_F16(aU[1], b1k1, aA);
      aB = MFMA_F16(aU[3], b1k3, aB);
      // next step's input projection (off critical path)
      {
        union { uint32_t u[4]; f16x8 v; } tmp;
        tmp.u[0] = pk16(pa[0], pa[1]); tmp.u[1] = pk16(pa[2], pa[3]);
        tmp.u[2] = pk16(pb[0], pb[1]); tmp.u[3] = pk16(pb[2], pb[3]);
        accI = MFMA_F16(aI1, tmp.v, bias1);
      }
      f32x4 s = aA + aB;
      const uint32_t lo = pk16(tanh_fast(s[0]), tanh_fast(s[1]));
      const uint32_t hi = pk16(tanh_fast(s[2]), tanh_fast(s[3]));
      *(uint2*)(H1n + woff) = make_uint2(lo, hi);
      sync_lds();
    };

    for (int t = 0; t < T; t += 4) {
      stepL1(t + 0, 0, q0a, q0b, q1a, q1b);
      stepL1(t + 1, 1, q1a, q1b, q2a, q2b);
      stepL1(t + 2, 0, q2a, q2b, q3a, q3b);
      stepL1(t + 3, 1, q3a, q3b, q0a, q0b);
    }
  } else {
    // ================= layer-2 wave: channels 16(w-8) .. +15 ================
    const int j = w - 8;
    f16x8 aI2[4], aR2[2];
#pragma unroll
    for (int k4 = 0; k4 < 4; ++k4)
      aI2[k4] = cvt8(Wih2 + (16 * j + n) * H1 + k4 * 32 + g * 8);
#pragma unroll
    for (int k2 = 0; k2 < 2; ++k2)
      aR2[k2] = cvt8(Whh2 + (16 * j + n) * H2 + k2 * 32 + g * 8);
    f32x4 bias2;
#pragma unroll
    for (int r = 0; r < 4; ++r) bias2[r] = bih2[16 * j + g * 4 + r] + bhh2[16 * j + g * 4 + r];

    int roff2[2];
#pragma unroll
    for (int k2 = 0; k2 < 2; ++k2)
      roff2[k2] = n * 128 + (((k2 * 4 + g) ^ (n & 7)) << 4);
    const int woff2 = n * 128 + (((2 * j + (g >> 1)) ^ (n & 7)) << 4) + (g & 1) * 8;

    auto stepL2 = [&](int t, int cur) {
      if (t > 0) {
        const char* H1c = (const char*)smem + cur * 4096;            // h1(t-1)
        const char* H2r = (const char*)smem + 8192 + (cur ^ 1) * 2048; // h2(t-2)
        char*       H2w = (char*)smem + 8192 + cur * 2048;           // h2(t-1)
        f16x8 b1k0 = *(const f16x8*)(H1c + roff1[0]);
        f16x8 b1k1 = *(const f16x8*)(H1c + roff1[1]);
        f16x8 b1k2 = *(const f16x8*)(H1c + roff1[2]);
        f16x8 b1k3 = *(const f16x8*)(H1c + roff1[3]);
        f16x8 b2k0 = *(const f16x8*)(H2r + roff2[0]);
        f16x8 b2k1 = *(const f16x8*)(H2r + roff2[1]);
        f32x4 zero = {0.f, 0.f, 0.f, 0.f};
        f32x4 cA = MFMA_F16(aI2[0], b1k0, zero);
        f32x4 cB = MFMA_F16(aI2[1], b1k1, zero);
        f32x4 cC = MFMA_F16(aR2[0], b2k0, bias2);
        cA = MFMA_F16(aI2[2], b1k2, cA);
        cB = MFMA_F16(aI2[3], b1k3, cB);
        cC = MFMA_F16(aR2[1], b2k1, cC);
        f32x4 s = cA + cB + cC;
        const uint32_t lo = pk16(tanh_fast(s[0]), tanh_fast(s[1]));
        const uint32_t hi = pk16(tanh_fast(s[2]), tanh_fast(s[3]));
        *(uint2*)(H2w + woff2) = make_uint2(lo, hi);
      }
      sync_lds();
    };

    for (int t = 0; t < T; t += 2) {
      stepL2(t + 0, 0);
      stepL2(t + 1, 1);
    }

    // final l2 step: h2(1023) from h1(1023) (H1[0]) and h2(1022) (H2[1])
    {
      const char* H1c = (const char*)smem;
      const char* H2r = (const char*)smem + 8192 + 2048;
      f16x8 b1k0 = *(const f16x8*)(H1c + roff1[0]);
      f16x8 b1k1 = *(const f16x8*)(H1c + roff1[1]);
      f16x8 b1k2 = *(const f16x8*)(H1c + roff1[2]);
      f16x8 b1k3 = *(const f16x8*)(H1c + roff1[3]);
      f16x8 b2k0 = *(const f16x8*)(H2r + roff2[0]);
      f16x8 b2k1 = *(const f16x8*)(H2r + roff2[1]);
      f32x4 zero = {0.f, 0.f, 0.f, 0.f};
      f32x4 cA = MFMA_F16(aI2[0], b1k0, zero);
      f32x4 cB = MFMA_F16(aI2[1], b1k1, zero);
      f32x4 cC = MFMA_F16(aR2[0], b2k0, bias2);
      cA = MFMA_F16(aI2[2], b1k2, cA);
      cB = MFMA_F16(aI2[3], b1k3, cB);
      cC = MFMA_F16(aR2[1], b2k1, cC);
      f32x4 s = cA + cB + cC;
      f32x4 hv;
#pragma unroll
      for (int r = 0; r < 4; ++r) hv[r] = tanh_fast(s[r]);
      *(f32x4*)(smem + 12288 + n * 256 + (16 * j + 4 * g) * 4) = hv;
    }
  }

  __syncthreads();

  // ---- FC head: logits[b][c] = b_fc[c] + sum_k h2f[b][k] * Wfc[c][k] ----
  if (tid < BB * 10) {
    const int b = tid / 10, c = tid % 10;
    const float* hrow = (const float*)(smem + 12288 + b * 256);
    float acc = bfc[c];
#pragma unroll 8
    for (int k = 0; k < 64; ++k) acc += hrow[k] * Wfc[c * 64 + k];
    out[(size_t)(b0 + b) * 10 + c] = acc;
  }
}

extern "C" void kernel_launch(void* const* d_in, const int* in_sizes, int n_in,
                              void* d_out, int out_size, void* d_ws, size_t ws_size,
                              hipStream_t stream) {
  const float* x    = (const float*)d_in[0];
  const float* Wih1 = (const float*)d_in[1];
  const float* Whh1 = (const float*)d_in[2];
  const float* bih1 = (const float*)d_in[3];
  const float* bhh1 = (const float*)d_in[4];
  const float* Wih2 = (const float*)d_in[5];
  const float* Whh2 = (const float*)d_in[6];
  const float* bih2 = (const float*)d_in[7];
  const float* bhh2 = (const float*)d_in[8];
  const float* Wfc  = (const float*)d_in[9];
  const float* bfc  = (const float*)d_in[10];

  hipLaunchKernelGGL(rnn_fused, dim3(512 / 16), dim3(768), 0, stream,
                     x, Wih1, Whh1, bih1, bhh1, Wih2, Whh2, bih2, bhh2,
                     Wfc, bfc, (float*)d_out);
}